// Round 22
// baseline (169.840 us; speedup 1.0000x reference)
//
#include <hip/hip_runtime.h>

#define B_ 8
#define C_ 256
#define H_ 96
#define W_ 128
#define HW_ (H_*W_)
#define PATCH_ 21
#define MAXD_ 20
// parity-packed workspace:
// ws1 granule idx: ((((b*8+cg)*H+h)*2+par)*64 + i)*4 + p      (w = 2i+par)
// ws2 granule idx: ((((b*8+cg)*H+h)*2+par)*88 + j)*4 + p      (wp = 2j+par, w2 = wp-20)
#define NG1_ (B_*8*H_*2*64*4)    // 3,145,728 granules
#define NG2_ (B_*8*H_*2*88*4)    // 4,325,376 granules
#define WS_NEED_ (((size_t)NG1_ + (size_t)NG2_) * 16)
#define NBLK2_ (B_*H_*6)         // 4608 blocks: (b, h2, dyo*2+thalf)
#define TSTR_ 68                 // transpose row stride (floats): 272B = 16B-multiple
#define NPACKROW_ (B_*8*H_)      // 6144 (b,cg,h) rows per input

typedef __fp16 half2_t __attribute__((ext_vector_type(2)));
typedef _Float16 f16x8 __attribute__((ext_vector_type(8)));
typedef float f32x4 __attribute__((ext_vector_type(4)));
typedef float f4_t __attribute__((ext_vector_type(4)));
typedef __fp16 h8_t __attribute__((ext_vector_type(8)));

__device__ __forceinline__ void gload_lds16(const f16x8* gsrc, f16x8* ldst) {
  __builtin_amdgcn_global_load_lds(
      (const __attribute__((address_space(1))) void*)gsrc,
      (__attribute__((address_space(3))) void*)ldst, 16, 0, 0);
}

// ---------------- prepass: LDS-staged, reads AND writes coalesced (r21-verified) ----------------
__global__ __launch_bounds__(256) void pack_kernel(
    const float* __restrict__ in1, const float* __restrict__ in2,
    f16x8* __restrict__ ws1, f16x8* __restrict__ ws2) {
  __shared__ float ldsf[32 * 130];
  const int tid = threadIdx.x;
  int blk = blockIdx.x;
  const bool is2 = blk >= NPACKROW_;
  if (is2) blk -= NPACKROW_;
  const int h  = blk % H_;
  const int cg = (blk / H_) & 7;
  const int b  = blk / (H_ * 8);
  const float* src = is2 ? in2 : in1;

  const float* srow = src + ((size_t)(b * C_ + cg * 32) * H_ + h) * W_;
#pragma unroll
  for (int it = 0; it < 16; ++it) {
    const int idx = it * 256 + tid;
    const int c = idx >> 7, w = idx & 127;
    ldsf[c * 130 + w] = srow[(size_t)c * HW_ + w];
  }
  __syncthreads();

  if (!is2) {
    f16x8* dst = ws1 + ((size_t)(b * 8 + cg) * H_ + h) * 512;
#pragma unroll
    for (int s = 0; s < 2; ++s) {
      const int g = tid + s * 256;
      const int p = g & 3, i = (g >> 2) & 63, par = g >> 8;
      const int w = 2 * i + par;
      f16x8 pk;
#pragma unroll
      for (int jj = 0; jj < 4; ++jj) {
        half2_t q = __builtin_amdgcn_cvt_pkrtz(ldsf[(p * 8 + 2 * jj) * 130 + w],
                                               ldsf[(p * 8 + 2 * jj + 1) * 130 + w]);
        pk[2 * jj]     = (_Float16)q.x;
        pk[2 * jj + 1] = (_Float16)q.y;
      }
      dst[g] = pk;
    }
  } else {
    f16x8* dst = ws2 + ((size_t)(b * 8 + cg) * H_ + h) * 704;
#pragma unroll
    for (int s = 0; s < 3; ++s) {
      const int g = tid + s * 256;
      if (g < 704) {
        const int p = g & 3, j = (g >> 2) % 88, par = g / 352;
        const int w2 = 2 * j + par - MAXD_;
        const bool v = (unsigned)w2 < (unsigned)W_;
        f16x8 pk;
#pragma unroll
        for (int jj = 0; jj < 4; ++jj) {
          float f0 = v ? ldsf[(p * 8 + 2 * jj) * 130 + w2] : 0.f;
          float f1 = v ? ldsf[(p * 8 + 2 * jj + 1) * 130 + w2] : 0.f;
          half2_t q = __builtin_amdgcn_cvt_pkrtz(f0, f1);
          pk[2 * jj]     = (_Float16)q.x;
          pk[2 * jj + 1] = (_Float16)q.y;
        }
        dst[g] = pk;
      }
    }
  }
}

// ---------------- zero-fill outputs whose h2 = h+2dy-20 is out of range ----------------
__global__ __launch_bounds__(128) void zfill_kernel(float* __restrict__ out) {
  const int t = threadIdx.x;
  int blk = blockIdx.x;
  const int slot = blk % 10; blk /= 10;
  const int dy = blk % 21; const int b = blk / 21;
  const int cnt = (dy < 10) ? (20 - 2 * dy) : ((dy > 10) ? (2 * dy - 20) : 0);
  const int hbase = (dy < 10) ? 0 : (116 - 2 * dy);
#pragma unroll
  for (int k = slot * 2; k < slot * 2 + 2; ++k) {
    if (k >= cnt) break;
    const int h = hbase + k;
    for (int dx = 0; dx < PATCH_; ++dx)
      out[(((size_t)b * 441 + dy * 21 + dx) * H_ + h) * W_ + t] = 0.f;
  }
}

// ---------------- main: parity-packed banded Gram, rotated chunk walk + setprio ----------------
__global__ __launch_bounds__(512, 2) void corr_pp(
    const f16x8* __restrict__ ws1,
    const f16x8* __restrict__ ws2,
    float* __restrict__ out) {
  // union: staging 8 chunks x 512 granules = 65536 B | transpose 8 x 21 x 68 floats = 45696 B
  __shared__ __align__(16) float lds_f[16384];
  f16x8* ldsB = (f16x8*)lds_f;

  const int wid  = threadIdx.x >> 6;
  const int lane = threadIdx.x & 63;
  const int n  = lane & 15;
  const int kg = lane >> 4;

  int blk = blockIdx.x;
  blk = (blk & 7) * (NBLK2_ / 8) + (blk >> 3);   // XCD-chunked
  const int ht = blk % 6;
  const int h2 = (blk / 6) % H_;
  const int b  = blk / (6 * H_);
  const int thalf = ht & 1;
  const int dyo   = ht >> 1;
  const int dy = dyo * 8 + wid;
  const int h  = h2 + 20 - 2 * dy;
  const bool valid = (dy <= MAXD_) && ((unsigned)h < (unsigned)H_);   // wave-uniform

  // ---- B tiles: (par,g), lane n -> j = 32*thalf+16g+n (clamp to zero granule 87) ----
  int boff[8];
#pragma unroll
  for (int par = 0; par < 2; ++par)
#pragma unroll
    for (int g = 0; g < 4; ++g) {
      int j = 32 * thalf + 16 * g + n;
      if (j > 87) j = 87;               // j>=74 stores zeros; clamped lanes feed dx>20 only
      boff[par * 4 + g] = (par * 88 + j) * 4 + kg;
    }
  const f16x8* ws2row = ws2 + ((size_t)(b * 8) * H_ + h2) * 704;   // 704 granules per (cg,h)
  const size_t sBseg = (size_t)H_ * 704;                           // per cg
  // ---- A per-lane base: tile (par,tau) offset = par*256 + tau*64 (granules) ----
  const f16x8* pAl = valid
      ? (ws1 + ((size_t)(b * 8) * H_ + h) * 512 + thalf * 128 + n * 4 + kg)
      : ws1;
  const size_t sA = (size_t)H_ * 512;

  // ---- stage: wave wid stages chunk wid (8 tiles x 1KB, contiguous bursts) ----
#pragma unroll
  for (int t = 0; t < 8; ++t)
    gload_lds16(ws2row + (size_t)wid * sBseg + boff[t], ldsB + wid * 512 + t * 64);

  f32x4 acc[4][3];   // [q = par*2+tau][d]
#pragma unroll
  for (int q = 0; q < 4; ++q)
#pragma unroll
    for (int d = 0; d < 3; ++d) acc[q][d] = f32x4{0.f, 0.f, 0.f, 0.f};

  // ---- rotated chunk order: wave wid walks cg = (wid+t)&7 (its own staged chunk first) ----
  f16x8 Ar[2][4];    // dbuf x [q]: granule offset (q>>1)*256 + (q&1)*64
  if (valid) {
#pragma unroll
    for (int q = 0; q < 4; ++q)
      Ar[0][q] = pAl[(size_t)wid * sA + (q >> 1) * 256 + (q & 1) * 64];
  }

  // the ONLY hot-path barrier
  asm volatile("s_waitcnt vmcnt(0)" ::: "memory");
  __builtin_amdgcn_s_barrier();
  __builtin_amdgcn_sched_barrier(0);

  if (valid) {
#pragma unroll
    for (int t = 0; t < 8; ++t) {
      const int cg = (wid + t) & 7;          // wave-uniform scalar
      if (t < 7) {
        const int cn = (wid + t + 1) & 7;
        const f16x8* pAc = pAl + (size_t)cn * sA;
#pragma unroll
        for (int q = 0; q < 4; ++q)
          Ar[(t + 1) & 1][q] = pAc[(q >> 1) * 256 + (q & 1) * 64];
        __builtin_amdgcn_sched_barrier(0);   // pin prefetch issue above compute
      }
      __builtin_amdgcn_s_setprio(1);         // T5: favor compute-phase waves
#pragma unroll
      for (int par = 0; par < 2; ++par) {
#pragma unroll
        for (int g = 0; g < 4; ++g) {
          const f16x8 Bu = ldsB[cg * 512 + (par * 4 + g) * 64 + lane];
#pragma unroll
          for (int tau = 0; tau < 2; ++tau) {
            const int d = g - tau;
            if (d >= 0 && d <= 2)
              acc[par * 2 + tau][d] = __builtin_amdgcn_mfma_f32_16x16x32_f16(
                  Ar[t & 1][par * 2 + tau], Bu, acc[par * 2 + tau][d], 0, 0, 0);
          }
        }
      }
      __builtin_amdgcn_s_setprio(0);
    }
  }

  __syncthreads();   // staging dead; reuse LDS for transpose
  float* slds = lds_f + wid * (PATCH_ * TSTR_);
  if (valid) {
    // writes: (tau,d,r) -> float2{par0,par1} at row dx=16d+n-m, col 32tau+8kg+2r  [r18-verified map]
#pragma unroll
    for (int tau = 0; tau < 2; ++tau)
#pragma unroll
      for (int d = 0; d < 3; ++d)
#pragma unroll
        for (int r = 0; r < 4; ++r) {
          const int m = kg * 4 + r;
          const int dxv = 16 * d + n - m;
          if (dxv >= 0 && dxv <= 20) {
            float2 v2 = make_float2(acc[tau][d][r], acc[2 + tau][d][r]);
            *(float2*)&slds[dxv * TSTR_ + 32 * tau + 8 * kg + 2 * r] = v2;
          }
        }
    // reads+stores: 5 groups of 4 rows (b128 + dwordx4), then row 20 scalar
    const float sc = 1.0f / (float)C_;
    const size_t obase = (((size_t)b * 441 + (size_t)dy * 21) * H_ + h) * W_ + thalf * 64;
    const int l4 = (lane & 15) * 4;
    const int rq = lane >> 4;
#pragma unroll
    for (int gq = 0; gq < 5; ++gq) {
      const int row = gq * 4 + rq;
      f4_t v = *(const f4_t*)&slds[row * TSTR_ + l4];
#pragma unroll
      for (int j = 0; j < 4; ++j) {
        float x = v[j] * sc;
        v[j] = (x >= 0.f) ? x : 0.1f * x;
      }
      *(f4_t*)&out[obase + (size_t)row * HW_ + l4] = v;
    }
    {
      float x = slds[20 * TSTR_ + lane] * sc;
      x = (x >= 0.f) ? x : 0.1f * x;
      out[obase + (size_t)20 * HW_ + lane] = x;
    }
  }
}

// ---------------- fallback (round-6 verified): f32 inputs, dot2 path ----------------
__device__ __forceinline__ float fdot2f(half2_t a, half2_t b, float c) {
  return __builtin_amdgcn_fdot2(a, b, c, false);
}
__device__ __forceinline__ int swz(int pos) { return pos ^ ((pos >> 3) & 7); }
#define P2_ 168
#define NBLK_ (B_*24*11)

__global__ __launch_bounds__(256, 2) void corr_kernel(
    const float* __restrict__ in1,
    const float* __restrict__ in2,
    float* __restrict__ out) {
  __shared__ h8_t lds[4 * 2 * P2_];
  const int tid  = threadIdx.x;
  const int wid  = tid >> 6;
  const int lane = tid & 63;
  const int l    = lane & 15;
  const int q    = (lane >> 4) & 1;
  const int gdy  = lane >> 5;
  int bid = blockIdx.x;
  bid = (bid & 7) * (NBLK_ / 8) + (bid >> 3);
  const int dyb = bid % 11;
  const int hg  = (bid / 11) % 24;
  const int b   = bid / (11 * 24);
  const int h   = hg * 4 + wid;
  const int dy   = 2 * dyb + gdy;
  const int w0   = 8 * l;
  const int rel0 = 20 * q;
  float acc[8][11];
#pragma unroll
  for (int j = 0; j < 8; ++j)
#pragma unroll
    for (int i = 0; i < 11; ++i) acc[j][i] = 0.f;
  const int wbase   = wid * (2 * P2_);
  const int ldsbase = wbase + gdy * P2_;
  for (int c0 = 0; c0 < C_; c0 += 8) {
#pragma unroll
    for (int s = lane; s < 2 * P2_; s += 64) {
      const int dyidx = (s >= P2_) ? 1 : 0;
      const int pos = s - P2_ * dyidx;
      const int h2 = h + 2 * (2 * dyb + dyidx) - MAXD_;
      const int w2 = pos - MAXD_;
      const bool v = ((unsigned)h2 < (unsigned)H_) && ((unsigned)w2 < (unsigned)W_);
      float f[8];
      if (v) {
        const float* bp = in2 + ((size_t)(b * C_ + c0) * H_ + h2) * W_ + w2;
#pragma unroll
        for (int j = 0; j < 8; ++j) f[j] = bp[(size_t)j * HW_];
      } else {
#pragma unroll
        for (int j = 0; j < 8; ++j) f[j] = 0.f;
      }
      h8_t pk;
#pragma unroll
      for (int jj = 0; jj < 4; ++jj) {
        half2_t p2 = __builtin_amdgcn_cvt_pkrtz(f[2 * jj], f[2 * jj + 1]);
        pk[2 * jj]     = p2.x;
        pk[2 * jj + 1] = p2.y;
      }
      lds[wbase + dyidx * P2_ + swz(pos)] = pk;
    }
    const float* a_base = in1 + ((size_t)(b * C_ + c0) * H_ + h) * W_ + w0;
    half2_t a2[8][4];
#pragma unroll
    for (int jj = 0; jj < 4; ++jj) {
      f4_t lo0 = *(const f4_t*)(a_base + (size_t)(2 * jj) * HW_);
      f4_t lo1 = *(const f4_t*)(a_base + (size_t)(2 * jj) * HW_ + 4);
      f4_t hi0 = *(const f4_t*)(a_base + (size_t)(2 * jj + 1) * HW_);
      f4_t hi1 = *(const f4_t*)(a_base + (size_t)(2 * jj + 1) * HW_ + 4);
#pragma unroll
      for (int j = 0; j < 4; ++j) {
        a2[j][jj]     = __builtin_amdgcn_cvt_pkrtz(lo0[j], hi0[j]);
        a2[j + 4][jj] = __builtin_amdgcn_cvt_pkrtz(lo1[j], hi1[j]);
      }
    }
    h8_t wv[8];
#pragma unroll
    for (int k = 0; k < 8; ++k)
      wv[k] = lds[ldsbase + swz(w0 + rel0 + k)];
#pragma unroll
    for (int i = 0; i < 11; ++i) {
#pragma unroll
      for (int j = 0; j < 8; ++j) {
        const h8_t wj = wv[(2 * i + j) & 7];
#pragma unroll
        for (int jj = 0; jj < 4; ++jj) {
          half2_t bb;
          bb.x = wj[2 * jj];
          bb.y = wj[2 * jj + 1];
          acc[j][i] = fdot2f(a2[j][jj], bb, acc[j][i]);
        }
      }
      if (i < 10) {
        wv[(2 * i + 8) & 7] = lds[ldsbase + swz(w0 + rel0 + 2 * i + 8)];
        wv[(2 * i + 9) & 7] = lds[ldsbase + swz(w0 + rel0 + 2 * i + 9)];
      }
    }
  }
  if (dy < PATCH_) {
    const float s = 1.f / (float)C_;
#pragma unroll
    for (int i = 0; i < 11; ++i) {
      if (q && i == 0) continue;
      const int dx = 10 * q + i;
      float* ob = out + ((size_t)(b * (PATCH_ * PATCH_) + dy * PATCH_ + dx) * H_ + h) * W_ + w0;
      f4_t v0, v1;
#pragma unroll
      for (int j = 0; j < 4; ++j) {
        float x = acc[j][i] * s;
        v0[j] = (x >= 0.f) ? x : 0.1f * x;
        float y = acc[j + 4][i] * s;
        v1[j] = (y >= 0.f) ? y : 0.1f * y;
      }
      *(f4_t*)ob = v0;
      *(f4_t*)(ob + 4) = v1;
    }
  }
}

extern "C" void kernel_launch(void* const* d_in, const int* in_sizes, int n_in,
                              void* d_out, int out_size, void* d_ws, size_t ws_size,
                              hipStream_t stream) {
  (void)in_sizes; (void)n_in; (void)out_size;
  const float* in1 = (const float*)d_in[0];
  const float* in2 = (const float*)d_in[1];
  float* out = (float*)d_out;

  if (ws_size >= WS_NEED_) {
    f16x8* ws1 = (f16x8*)d_ws;
    f16x8* ws2 = ws1 + NG1_;
    pack_kernel<<<dim3(2 * NPACKROW_), dim3(256), 0, stream>>>(in1, in2, ws1, ws2);
    zfill_kernel<<<dim3(B_ * PATCH_ * 10), dim3(128), 0, stream>>>(out);
    corr_pp<<<dim3(NBLK2_), dim3(512), 0, stream>>>(ws1, ws2, out);
  } else {
    corr_kernel<<<dim3(NBLK_), dim3(256), 0, stream>>>(in1, in2, out);
  }
}

// Round 23
// 164.291 us; speedup vs baseline: 1.0338x; 1.0338x over previous
//
#include <hip/hip_runtime.h>

#define B_ 8
#define C_ 256
#define H_ 96
#define W_ 128
#define HW_ (H_*W_)
#define PATCH_ 21
#define MAXD_ 20
// parity-packed workspace:
// ws1 granule idx: ((((b*8+cg)*H+h)*2+par)*64 + i)*4 + p      (w = 2i+par)
// ws2 granule idx: ((((b*8+cg)*H+h)*2+par)*88 + j)*4 + p      (wp = 2j+par, w2 = wp-20)
#define NG1_ (B_*8*H_*2*64*4)    // 3,145,728 granules
#define NG2_ (B_*8*H_*2*88*4)    // 4,325,376 granules
#define WS_NEED_ (((size_t)NG1_ + (size_t)NG2_) * 16)
#define NBLK2_ (B_*H_*6)         // 4608 blocks: (b, h2, dyo*2+thalf)
#define TSTR_ 68                 // transpose row stride (floats): 272B = 16B-multiple
#define NPACKROW_ (B_*8*H_)      // 6144 (b,cg,h) rows per input

typedef __fp16 half2_t __attribute__((ext_vector_type(2)));
typedef _Float16 f16x8 __attribute__((ext_vector_type(8)));
typedef float f32x4 __attribute__((ext_vector_type(4)));
typedef float f4_t __attribute__((ext_vector_type(4)));
typedef __fp16 h8_t __attribute__((ext_vector_type(8)));

__device__ __forceinline__ void gload_lds16(const f16x8* gsrc, f16x8* ldst) {
  __builtin_amdgcn_global_load_lds(
      (const __attribute__((address_space(1))) void*)gsrc,
      (__attribute__((address_space(3))) void*)ldst, 16, 0, 0);
}

// ---------------- prepass: LDS-staged, reads AND writes coalesced (r21-verified) ----------------
__global__ __launch_bounds__(256) void pack_kernel(
    const float* __restrict__ in1, const float* __restrict__ in2,
    f16x8* __restrict__ ws1, f16x8* __restrict__ ws2) {
  __shared__ float ldsf[32 * 130];
  const int tid = threadIdx.x;
  int blk = blockIdx.x;
  const bool is2 = blk >= NPACKROW_;
  if (is2) blk -= NPACKROW_;
  const int h  = blk % H_;
  const int cg = (blk / H_) & 7;
  const int b  = blk / (H_ * 8);
  const float* src = is2 ? in2 : in1;

  const float* srow = src + ((size_t)(b * C_ + cg * 32) * H_ + h) * W_;
#pragma unroll
  for (int it = 0; it < 16; ++it) {
    const int idx = it * 256 + tid;
    const int c = idx >> 7, w = idx & 127;
    ldsf[c * 130 + w] = srow[(size_t)c * HW_ + w];
  }
  __syncthreads();

  if (!is2) {
    f16x8* dst = ws1 + ((size_t)(b * 8 + cg) * H_ + h) * 512;
#pragma unroll
    for (int s = 0; s < 2; ++s) {
      const int g = tid + s * 256;
      const int p = g & 3, i = (g >> 2) & 63, par = g >> 8;
      const int w = 2 * i + par;
      f16x8 pk;
#pragma unroll
      for (int jj = 0; jj < 4; ++jj) {
        half2_t q = __builtin_amdgcn_cvt_pkrtz(ldsf[(p * 8 + 2 * jj) * 130 + w],
                                               ldsf[(p * 8 + 2 * jj + 1) * 130 + w]);
        pk[2 * jj]     = (_Float16)q.x;
        pk[2 * jj + 1] = (_Float16)q.y;
      }
      dst[g] = pk;
    }
  } else {
    f16x8* dst = ws2 + ((size_t)(b * 8 + cg) * H_ + h) * 704;
#pragma unroll
    for (int s = 0; s < 3; ++s) {
      const int g = tid + s * 256;
      if (g < 704) {
        const int p = g & 3, j = (g >> 2) % 88, par = g / 352;
        const int w2 = 2 * j + par - MAXD_;
        const bool v = (unsigned)w2 < (unsigned)W_;
        f16x8 pk;
#pragma unroll
        for (int jj = 0; jj < 4; ++jj) {
          float f0 = v ? ldsf[(p * 8 + 2 * jj) * 130 + w2] : 0.f;
          float f1 = v ? ldsf[(p * 8 + 2 * jj + 1) * 130 + w2] : 0.f;
          half2_t q = __builtin_amdgcn_cvt_pkrtz(f0, f1);
          pk[2 * jj]     = (_Float16)q.x;
          pk[2 * jj + 1] = (_Float16)q.y;
        }
        dst[g] = pk;
      }
    }
  }
}

// ---------------- main: parity-packed banded Gram + merged zero-fill ----------------
__global__ __launch_bounds__(512, 2) void corr_pp(
    const f16x8* __restrict__ ws1,
    const f16x8* __restrict__ ws2,
    float* __restrict__ out) {
  // union: staging 8 chunks x 512 granules = 65536 B | transpose 8 x 21 x 68 floats = 45696 B
  __shared__ __align__(16) float lds_f[16384];
  f16x8* ldsB = (f16x8*)lds_f;

  const int wid  = threadIdx.x >> 6;
  const int lane = threadIdx.x & 63;
  const int n  = lane & 15;
  const int kg = lane >> 4;

  int blk = blockIdx.x;
  blk = (blk & 7) * (NBLK2_ / 8) + (blk >> 3);   // XCD-chunked
  const int ht = blk % 6;
  const int h2 = (blk / 6) % H_;
  const int b  = blk / (6 * H_);
  const int thalf = ht & 1;
  const int dyo   = ht >> 1;
  const int dy = dyo * 8 + wid;
  const int h  = h2 + 20 - 2 * dy;
  const bool valid = (dy <= MAXD_) && ((unsigned)h < (unsigned)H_);   // wave-uniform

  // ---- B tiles: (par,g), lane n -> j = 32*thalf+16g+n (clamp to zero granule 87) ----
  int boff[8];
#pragma unroll
  for (int par = 0; par < 2; ++par)
#pragma unroll
    for (int g = 0; g < 4; ++g) {
      int j = 32 * thalf + 16 * g + n;
      if (j > 87) j = 87;               // j>=74 stores zeros; clamped lanes feed dx>20 only
      boff[par * 4 + g] = (par * 88 + j) * 4 + kg;
    }
  const f16x8* ws2row = ws2 + ((size_t)(b * 8) * H_ + h2) * 704;   // 704 granules per (cg,h)
  const size_t sBseg = (size_t)H_ * 704;                           // per cg
  // ---- A per-lane base: tile (par,tau) offset = par*256 + tau*64 (granules) ----
  const f16x8* pAl = valid
      ? (ws1 + ((size_t)(b * 8) * H_ + h) * 512 + thalf * 128 + n * 4 + kg)
      : ws1;
  const size_t sA = (size_t)H_ * 512;

  // ---- stage: wave wid stages chunk wid (8 tiles x 1KB, contiguous bursts) ----
#pragma unroll
  for (int t = 0; t < 8; ++t)
    gload_lds16(ws2row + (size_t)wid * sBseg + boff[t], ldsB + wid * 512 + t * 64);

  f32x4 acc[4][3];   // [q = par*2+tau][d]
#pragma unroll
  for (int q = 0; q < 4; ++q)
#pragma unroll
    for (int d = 0; d < 3; ++d) acc[q][d] = f32x4{0.f, 0.f, 0.f, 0.f};

  f16x8 Ar[2][4];    // dbuf x [q]: granule offset (q>>1)*256 + (q&1)*64
  if (valid) {
#pragma unroll
    for (int q = 0; q < 4; ++q) Ar[0][q] = pAl[(q >> 1) * 256 + (q & 1) * 64];
  }

  // the ONLY hot-path barrier
  asm volatile("s_waitcnt vmcnt(0)" ::: "memory");
  __builtin_amdgcn_s_barrier();
  __builtin_amdgcn_sched_barrier(0);

  if (valid) {
#pragma unroll
    for (int cg = 0; cg < 8; ++cg) {
      if (cg < 7) {
#pragma unroll
        for (int q = 0; q < 4; ++q)
          Ar[(cg + 1) & 1][q] = pAl[(size_t)(cg + 1) * sA + (q >> 1) * 256 + (q & 1) * 64];
        __builtin_amdgcn_sched_barrier(0);   // pin prefetch issue above compute
      }
#pragma unroll
      for (int par = 0; par < 2; ++par) {
#pragma unroll
        for (int g = 0; g < 4; ++g) {
          const f16x8 Bu = ldsB[cg * 512 + (par * 4 + g) * 64 + lane];
#pragma unroll
          for (int tau = 0; tau < 2; ++tau) {
            const int d = g - tau;
            if (d >= 0 && d <= 2)
              acc[par * 2 + tau][d] = __builtin_amdgcn_mfma_f32_16x16x32_f16(
                  Ar[cg & 1][par * 2 + tau], Bu, acc[par * 2 + tau][d], 0, 0, 0);
          }
        }
      }
    }
  }

  __syncthreads();   // staging dead; reuse LDS for transpose
  float* slds = lds_f + wid * (PATCH_ * TSTR_);
  if (valid) {
    // writes: (tau,d,r) -> float2{par0,par1} at row dx=16d+n-m, col 32tau+8kg+2r  [r18-verified map]
#pragma unroll
    for (int tau = 0; tau < 2; ++tau)
#pragma unroll
      for (int d = 0; d < 3; ++d)
#pragma unroll
        for (int r = 0; r < 4; ++r) {
          const int m = kg * 4 + r;
          const int dxv = 16 * d + n - m;
          if (dxv >= 0 && dxv <= 20) {
            float2 v2 = make_float2(acc[tau][d][r], acc[2 + tau][d][r]);
            *(float2*)&slds[dxv * TSTR_ + 32 * tau + 8 * kg + 2 * r] = v2;
          }
        }
    // reads+stores: 5 groups of 4 rows (b128 + dwordx4), then row 20 scalar
    const float sc = 1.0f / (float)C_;
    const size_t obase = (((size_t)b * 441 + (size_t)dy * 21) * H_ + h) * W_ + thalf * 64;
    const int l4 = (lane & 15) * 4;
    const int rq = lane >> 4;
#pragma unroll
    for (int gq = 0; gq < 5; ++gq) {
      const int row = gq * 4 + rq;
      f4_t v = *(const f4_t*)&slds[row * TSTR_ + l4];
#pragma unroll
      for (int j = 0; j < 4; ++j) {
        float x = v[j] * sc;
        v[j] = (x >= 0.f) ? x : 0.1f * x;
      }
      *(f4_t*)&out[obase + (size_t)row * HW_ + l4] = v;
    }
    {
      float x = slds[20 * TSTR_ + lane] * sc;
      x = (x >= 0.f) ? x : 0.1f * x;
      out[obase + (size_t)20 * HW_ + lane] = x;
    }
  } else if (dy <= MAXD_) {
    // merged zero-fill: this wave's (h2,dy) has h out of range; it bijects onto the
    // output row (dy, h') whose h2' = h'+2dy-20 is out of range:
    //   dy<10: h2 in [76+2dy,96) -> h' = h2-76-2dy in [0,20-2dy)
    //   dy>10: h2 in [0,2dy-20)  -> h' = h2+116-2dy in [116-2dy,96)
    const int hp = (dy < 10) ? (h2 - 76 - 2 * dy) : (h2 + 116 - 2 * dy);
    if ((unsigned)hp < (unsigned)H_) {
      const size_t obase = (((size_t)b * 441 + (size_t)dy * 21) * H_ + hp) * W_ + thalf * 64;
#pragma unroll
      for (int dx = 0; dx < PATCH_; ++dx)
        out[obase + (size_t)dx * HW_ + lane] = 0.f;
    }
  }
}

// ---------------- fallback (round-6 verified): f32 inputs, dot2 path ----------------
__device__ __forceinline__ float fdot2f(half2_t a, half2_t b, float c) {
  return __builtin_amdgcn_fdot2(a, b, c, false);
}
__device__ __forceinline__ int swz(int pos) { return pos ^ ((pos >> 3) & 7); }
#define P2_ 168
#define NBLK_ (B_*24*11)

__global__ __launch_bounds__(256, 2) void corr_kernel(
    const float* __restrict__ in1,
    const float* __restrict__ in2,
    float* __restrict__ out) {
  __shared__ h8_t lds[4 * 2 * P2_];
  const int tid  = threadIdx.x;
  const int wid  = tid >> 6;
  const int lane = tid & 63;
  const int l    = lane & 15;
  const int q    = (lane >> 4) & 1;
  const int gdy  = lane >> 5;
  int bid = blockIdx.x;
  bid = (bid & 7) * (NBLK_ / 8) + (bid >> 3);
  const int dyb = bid % 11;
  const int hg  = (bid / 11) % 24;
  const int b   = bid / (11 * 24);
  const int h   = hg * 4 + wid;
  const int dy   = 2 * dyb + gdy;
  const int w0   = 8 * l;
  const int rel0 = 20 * q;
  float acc[8][11];
#pragma unroll
  for (int j = 0; j < 8; ++j)
#pragma unroll
    for (int i = 0; i < 11; ++i) acc[j][i] = 0.f;
  const int wbase   = wid * (2 * P2_);
  const int ldsbase = wbase + gdy * P2_;
  for (int c0 = 0; c0 < C_; c0 += 8) {
#pragma unroll
    for (int s = lane; s < 2 * P2_; s += 64) {
      const int dyidx = (s >= P2_) ? 1 : 0;
      const int pos = s - P2_ * dyidx;
      const int h2 = h + 2 * (2 * dyb + dyidx) - MAXD_;
      const int w2 = pos - MAXD_;
      const bool v = ((unsigned)h2 < (unsigned)H_) && ((unsigned)w2 < (unsigned)W_);
      float f[8];
      if (v) {
        const float* bp = in2 + ((size_t)(b * C_ + c0) * H_ + h2) * W_ + w2;
#pragma unroll
        for (int j = 0; j < 8; ++j) f[j] = bp[(size_t)j * HW_];
      } else {
#pragma unroll
        for (int j = 0; j < 8; ++j) f[j] = 0.f;
      }
      h8_t pk;
#pragma unroll
      for (int jj = 0; jj < 4; ++jj) {
        half2_t p2 = __builtin_amdgcn_cvt_pkrtz(f[2 * jj], f[2 * jj + 1]);
        pk[2 * jj]     = p2.x;
        pk[2 * jj + 1] = p2.y;
      }
      lds[wbase + dyidx * P2_ + swz(pos)] = pk;
    }
    const float* a_base = in1 + ((size_t)(b * C_ + c0) * H_ + h) * W_ + w0;
    half2_t a2[8][4];
#pragma unroll
    for (int jj = 0; jj < 4; ++jj) {
      f4_t lo0 = *(const f4_t*)(a_base + (size_t)(2 * jj) * HW_);
      f4_t lo1 = *(const f4_t*)(a_base + (size_t)(2 * jj) * HW_ + 4);
      f4_t hi0 = *(const f4_t*)(a_base + (size_t)(2 * jj + 1) * HW_);
      f4_t hi1 = *(const f4_t*)(a_base + (size_t)(2 * jj + 1) * HW_ + 4);
#pragma unroll
      for (int j = 0; j < 4; ++j) {
        a2[j][jj]     = __builtin_amdgcn_cvt_pkrtz(lo0[j], hi0[j]);
        a2[j + 4][jj] = __builtin_amdgcn_cvt_pkrtz(lo1[j], hi1[j]);
      }
    }
    h8_t wv[8];
#pragma unroll
    for (int k = 0; k < 8; ++k)
      wv[k] = lds[ldsbase + swz(w0 + rel0 + k)];
#pragma unroll
    for (int i = 0; i < 11; ++i) {
#pragma unroll
      for (int j = 0; j < 8; ++j) {
        const h8_t wj = wv[(2 * i + j) & 7];
#pragma unroll
        for (int jj = 0; jj < 4; ++jj) {
          half2_t bb;
          bb.x = wj[2 * jj];
          bb.y = wj[2 * jj + 1];
          acc[j][i] = fdot2f(a2[j][jj], bb, acc[j][i]);
        }
      }
      if (i < 10) {
        wv[(2 * i + 8) & 7] = lds[ldsbase + swz(w0 + rel0 + 2 * i + 8)];
        wv[(2 * i + 9) & 7] = lds[ldsbase + swz(w0 + rel0 + 2 * i + 9)];
      }
    }
  }
  if (dy < PATCH_) {
    const float s = 1.f / (float)C_;
#pragma unroll
    for (int i = 0; i < 11; ++i) {
      if (q && i == 0) continue;
      const int dx = 10 * q + i;
      float* ob = out + ((size_t)(b * (PATCH_ * PATCH_) + dy * PATCH_ + dx) * H_ + h) * W_ + w0;
      f4_t v0, v1;
#pragma unroll
      for (int j = 0; j < 4; ++j) {
        float x = acc[j][i] * s;
        v0[j] = (x >= 0.f) ? x : 0.1f * x;
        float y = acc[j + 4][i] * s;
        v1[j] = (y >= 0.f) ? y : 0.1f * y;
      }
      *(f4_t*)ob = v0;
      *(f4_t*)(ob + 4) = v1;
    }
  }
}

extern "C" void kernel_launch(void* const* d_in, const int* in_sizes, int n_in,
                              void* d_out, int out_size, void* d_ws, size_t ws_size,
                              hipStream_t stream) {
  (void)in_sizes; (void)n_in; (void)out_size;
  const float* in1 = (const float*)d_in[0];
  const float* in2 = (const float*)d_in[1];
  float* out = (float*)d_out;

  if (ws_size >= WS_NEED_) {
    f16x8* ws1 = (f16x8*)d_ws;
    f16x8* ws2 = ws1 + NG1_;
    pack_kernel<<<dim3(2 * NPACKROW_), dim3(256), 0, stream>>>(in1, in2, ws1, ws2);
    corr_pp<<<dim3(NBLK2_), dim3(512), 0, stream>>>(ws1, ws2, out);
  } else {
    corr_kernel<<<dim3(NBLK_), dim3(256), 0, stream>>>(in1, in2, out);
  }
}

// Round 24
// 162.717 us; speedup vs baseline: 1.0438x; 1.0097x over previous
//
#include <hip/hip_runtime.h>

#define B_ 8
#define C_ 256
#define H_ 96
#define W_ 128
#define HW_ (H_*W_)
#define PATCH_ 21
#define MAXD_ 20
// parity-packed workspace:
// ws1 granule idx: ((((b*8+cg)*H+h)*2+par)*64 + i)*4 + p      (w = 2i+par)
// ws2 granule idx: ((((b*8+cg)*H+h)*2+par)*88 + j)*4 + p      (wp = 2j+par, w2 = wp-20)
#define NG1_ (B_*8*H_*2*64*4)    // 3,145,728 granules
#define NG2_ (B_*8*H_*2*88*4)    // 4,325,376 granules
#define WS_NEED_ (((size_t)NG1_ + (size_t)NG2_) * 16)
#define NBLK2_ (B_*H_*6)         // 4608 blocks: (b, h2, dyo*2+thalf)
#define TSTR_ 68                 // transpose row stride (floats): 272B = 16B-multiple
#define NPACKROW_ (B_*8*H_)      // 6144 (b,cg,h) rows per input

typedef __fp16 half2_t __attribute__((ext_vector_type(2)));
typedef _Float16 f16x8 __attribute__((ext_vector_type(8)));
typedef float f32x4 __attribute__((ext_vector_type(4)));
typedef float f4_t __attribute__((ext_vector_type(4)));
typedef __fp16 h8_t __attribute__((ext_vector_type(8)));

__device__ __forceinline__ void gload_lds16(const f16x8* gsrc, f16x8* ldst) {
  __builtin_amdgcn_global_load_lds(
      (const __attribute__((address_space(1))) void*)gsrc,
      (__attribute__((address_space(3))) void*)ldst, 16, 0, 0);
}

// ---------------- prepass: LDS-staged, reads AND writes coalesced (r21-verified) ----------------
__global__ __launch_bounds__(256) void pack_kernel(
    const float* __restrict__ in1, const float* __restrict__ in2,
    f16x8* __restrict__ ws1, f16x8* __restrict__ ws2) {
  __shared__ float ldsf[32 * 130];
  const int tid = threadIdx.x;
  int blk = blockIdx.x;
  const bool is2 = blk >= NPACKROW_;
  if (is2) blk -= NPACKROW_;
  const int h  = blk % H_;
  const int cg = (blk / H_) & 7;
  const int b  = blk / (H_ * 8);
  const float* src = is2 ? in2 : in1;

  const float* srow = src + ((size_t)(b * C_ + cg * 32) * H_ + h) * W_;
#pragma unroll
  for (int it = 0; it < 16; ++it) {
    const int idx = it * 256 + tid;
    const int c = idx >> 7, w = idx & 127;
    ldsf[c * 130 + w] = srow[(size_t)c * HW_ + w];
  }
  __syncthreads();

  if (!is2) {
    f16x8* dst = ws1 + ((size_t)(b * 8 + cg) * H_ + h) * 512;
#pragma unroll
    for (int s = 0; s < 2; ++s) {
      const int g = tid + s * 256;
      const int p = g & 3, i = (g >> 2) & 63, par = g >> 8;
      const int w = 2 * i + par;
      f16x8 pk;
#pragma unroll
      for (int jj = 0; jj < 4; ++jj) {
        half2_t q = __builtin_amdgcn_cvt_pkrtz(ldsf[(p * 8 + 2 * jj) * 130 + w],
                                               ldsf[(p * 8 + 2 * jj + 1) * 130 + w]);
        pk[2 * jj]     = (_Float16)q.x;
        pk[2 * jj + 1] = (_Float16)q.y;
      }
      dst[g] = pk;
    }
  } else {
    f16x8* dst = ws2 + ((size_t)(b * 8 + cg) * H_ + h) * 704;
#pragma unroll
    for (int s = 0; s < 3; ++s) {
      const int g = tid + s * 256;
      if (g < 704) {
        const int p = g & 3, j = (g >> 2) % 88, par = g / 352;
        const int w2 = 2 * j + par - MAXD_;
        const bool v = (unsigned)w2 < (unsigned)W_;
        f16x8 pk;
#pragma unroll
        for (int jj = 0; jj < 4; ++jj) {
          float f0 = v ? ldsf[(p * 8 + 2 * jj) * 130 + w2] : 0.f;
          float f1 = v ? ldsf[(p * 8 + 2 * jj + 1) * 130 + w2] : 0.f;
          half2_t q = __builtin_amdgcn_cvt_pkrtz(f0, f1);
          pk[2 * jj]     = (_Float16)q.x;
          pk[2 * jj + 1] = (_Float16)q.y;
        }
        dst[g] = pk;
      }
    }
  }
}

// ---------------- main: parity-packed banded Gram + merged zero-fill, Bf[4] batch ----------------
__global__ __launch_bounds__(512, 2) void corr_pp(
    const f16x8* __restrict__ ws1,
    const f16x8* __restrict__ ws2,
    float* __restrict__ out) {
  // union: staging 8 chunks x 512 granules = 65536 B | transpose 8 x 21 x 68 floats = 45696 B
  __shared__ __align__(16) float lds_f[16384];
  f16x8* ldsB = (f16x8*)lds_f;

  const int wid  = threadIdx.x >> 6;
  const int lane = threadIdx.x & 63;
  const int n  = lane & 15;
  const int kg = lane >> 4;

  int blk = blockIdx.x;
  blk = (blk & 7) * (NBLK2_ / 8) + (blk >> 3);   // XCD-chunked
  const int ht = blk % 6;
  const int h2 = (blk / 6) % H_;
  const int b  = blk / (6 * H_);
  const int thalf = ht & 1;
  const int dyo   = ht >> 1;
  const int dy = dyo * 8 + wid;
  const int h  = h2 + 20 - 2 * dy;
  const bool valid = (dy <= MAXD_) && ((unsigned)h < (unsigned)H_);   // wave-uniform

  // ---- B tiles: (par,g), lane n -> j = 32*thalf+16g+n (clamp to zero granule 87) ----
  int boff[8];
#pragma unroll
  for (int par = 0; par < 2; ++par)
#pragma unroll
    for (int g = 0; g < 4; ++g) {
      int j = 32 * thalf + 16 * g + n;
      if (j > 87) j = 87;               // j>=74 stores zeros; clamped lanes feed dx>20 only
      boff[par * 4 + g] = (par * 88 + j) * 4 + kg;
    }
  const f16x8* ws2row = ws2 + ((size_t)(b * 8) * H_ + h2) * 704;   // 704 granules per (cg,h)
  const size_t sBseg = (size_t)H_ * 704;                           // per cg
  // ---- A per-lane base: tile (par,tau) offset = par*256 + tau*64 (granules) ----
  const f16x8* pAl = valid
      ? (ws1 + ((size_t)(b * 8) * H_ + h) * 512 + thalf * 128 + n * 4 + kg)
      : ws1;
  const size_t sA = (size_t)H_ * 512;

  // ---- stage: wave wid stages chunk wid (8 tiles x 1KB, contiguous bursts) ----
#pragma unroll
  for (int t = 0; t < 8; ++t)
    gload_lds16(ws2row + (size_t)wid * sBseg + boff[t], ldsB + wid * 512 + t * 64);

  f32x4 acc[4][3];   // [q = par*2+tau][d]
#pragma unroll
  for (int q = 0; q < 4; ++q)
#pragma unroll
    for (int d = 0; d < 3; ++d) acc[q][d] = f32x4{0.f, 0.f, 0.f, 0.f};

  f16x8 Ar[2][4];    // dbuf x [q]: granule offset (q>>1)*256 + (q&1)*64
  if (valid) {
#pragma unroll
    for (int q = 0; q < 4; ++q) Ar[0][q] = pAl[(q >> 1) * 256 + (q & 1) * 64];
  }

  // the ONLY hot-path barrier
  asm volatile("s_waitcnt vmcnt(0)" ::: "memory");
  __builtin_amdgcn_s_barrier();
  __builtin_amdgcn_sched_barrier(0);

  if (valid) {
#pragma unroll
    for (int cg = 0; cg < 8; ++cg) {
      if (cg < 7) {
#pragma unroll
        for (int q = 0; q < 4; ++q)
          Ar[(cg + 1) & 1][q] = pAl[(size_t)(cg + 1) * sA + (q >> 1) * 256 + (q & 1) * 64];
        __builtin_amdgcn_sched_barrier(0);   // pin prefetch issue above compute
      }
#pragma unroll
      for (int par = 0; par < 2; ++par) {
        // batch-issue this parity's 4 B reads; fence pins them ahead of the MFMAs.
        // region after fence (par0 MFMAs) can still absorb par1's reads + A-prefetch.
        f16x8 Bf[4];
#pragma unroll
        for (int g = 0; g < 4; ++g)
          Bf[g] = ldsB[cg * 512 + (par * 4 + g) * 64 + lane];
        __builtin_amdgcn_sched_barrier(0);
#pragma unroll
        for (int g = 0; g < 4; ++g) {
#pragma unroll
          for (int tau = 0; tau < 2; ++tau) {
            const int d = g - tau;
            if (d >= 0 && d <= 2)
              acc[par * 2 + tau][d] = __builtin_amdgcn_mfma_f32_16x16x32_f16(
                  Ar[cg & 1][par * 2 + tau], Bf[g], acc[par * 2 + tau][d], 0, 0, 0);
          }
        }
      }
    }
  }

  __syncthreads();   // staging dead; reuse LDS for transpose
  float* slds = lds_f + wid * (PATCH_ * TSTR_);
  if (valid) {
    // writes: (tau,d,r) -> float2{par0,par1} at row dx=16d+n-m, col 32tau+8kg+2r  [r18-verified map]
#pragma unroll
    for (int tau = 0; tau < 2; ++tau)
#pragma unroll
      for (int d = 0; d < 3; ++d)
#pragma unroll
        for (int r = 0; r < 4; ++r) {
          const int m = kg * 4 + r;
          const int dxv = 16 * d + n - m;
          if (dxv >= 0 && dxv <= 20) {
            float2 v2 = make_float2(acc[tau][d][r], acc[2 + tau][d][r]);
            *(float2*)&slds[dxv * TSTR_ + 32 * tau + 8 * kg + 2 * r] = v2;
          }
        }
    // reads+stores: 5 groups of 4 rows (b128 + dwordx4), then row 20 scalar
    const float sc = 1.0f / (float)C_;
    const size_t obase = (((size_t)b * 441 + (size_t)dy * 21) * H_ + h) * W_ + thalf * 64;
    const int l4 = (lane & 15) * 4;
    const int rq = lane >> 4;
#pragma unroll
    for (int gq = 0; gq < 5; ++gq) {
      const int row = gq * 4 + rq;
      f4_t v = *(const f4_t*)&slds[row * TSTR_ + l4];
#pragma unroll
      for (int j = 0; j < 4; ++j) {
        float x = v[j] * sc;
        v[j] = (x >= 0.f) ? x : 0.1f * x;
      }
      *(f4_t*)&out[obase + (size_t)row * HW_ + l4] = v;
    }
    {
      float x = slds[20 * TSTR_ + lane] * sc;
      x = (x >= 0.f) ? x : 0.1f * x;
      out[obase + (size_t)20 * HW_ + lane] = x;
    }
  } else if (dy <= MAXD_) {
    // merged zero-fill: this wave's (h2,dy) has h out of range; it bijects onto the
    // output row (dy, h') whose h2' = h'+2dy-20 is out of range:
    //   dy<10: h2 in [76+2dy,96) -> h' = h2-76-2dy in [0,20-2dy)
    //   dy>10: h2 in [0,2dy-20)  -> h' = h2+116-2dy in [116-2dy,96)
    const int hp = (dy < 10) ? (h2 - 76 - 2 * dy) : (h2 + 116 - 2 * dy);
    if ((unsigned)hp < (unsigned)H_) {
      const size_t obase = (((size_t)b * 441 + (size_t)dy * 21) * H_ + hp) * W_ + thalf * 64;
#pragma unroll
      for (int dx = 0; dx < PATCH_; ++dx)
        out[obase + (size_t)dx * HW_ + lane] = 0.f;
    }
  }
}

// ---------------- fallback (round-6 verified): f32 inputs, dot2 path ----------------
__device__ __forceinline__ float fdot2f(half2_t a, half2_t b, float c) {
  return __builtin_amdgcn_fdot2(a, b, c, false);
}
__device__ __forceinline__ int swz(int pos) { return pos ^ ((pos >> 3) & 7); }
#define P2_ 168
#define NBLK_ (B_*24*11)

__global__ __launch_bounds__(256, 2) void corr_kernel(
    const float* __restrict__ in1,
    const float* __restrict__ in2,
    float* __restrict__ out) {
  __shared__ h8_t lds[4 * 2 * P2_];
  const int tid  = threadIdx.x;
  const int wid  = tid >> 6;
  const int lane = tid & 63;
  const int l    = lane & 15;
  const int q    = (lane >> 4) & 1;
  const int gdy  = lane >> 5;
  int bid = blockIdx.x;
  bid = (bid & 7) * (NBLK_ / 8) + (bid >> 3);
  const int dyb = bid % 11;
  const int hg  = (bid / 11) % 24;
  const int b   = bid / (11 * 24);
  const int h   = hg * 4 + wid;
  const int dy   = 2 * dyb + gdy;
  const int w0   = 8 * l;
  const int rel0 = 20 * q;
  float acc[8][11];
#pragma unroll
  for (int j = 0; j < 8; ++j)
#pragma unroll
    for (int i = 0; i < 11; ++i) acc[j][i] = 0.f;
  const int wbase   = wid * (2 * P2_);
  const int ldsbase = wbase + gdy * P2_;
  for (int c0 = 0; c0 < C_; c0 += 8) {
#pragma unroll
    for (int s = lane; s < 2 * P2_; s += 64) {
      const int dyidx = (s >= P2_) ? 1 : 0;
      const int pos = s - P2_ * dyidx;
      const int h2 = h + 2 * (2 * dyb + dyidx) - MAXD_;
      const int w2 = pos - MAXD_;
      const bool v = ((unsigned)h2 < (unsigned)H_) && ((unsigned)w2 < (unsigned)W_);
      float f[8];
      if (v) {
        const float* bp = in2 + ((size_t)(b * C_ + c0) * H_ + h2) * W_ + w2;
#pragma unroll
        for (int j = 0; j < 8; ++j) f[j] = bp[(size_t)j * HW_];
      } else {
#pragma unroll
        for (int j = 0; j < 8; ++j) f[j] = 0.f;
      }
      h8_t pk;
#pragma unroll
      for (int jj = 0; jj < 4; ++jj) {
        half2_t p2 = __builtin_amdgcn_cvt_pkrtz(f[2 * jj], f[2 * jj + 1]);
        pk[2 * jj]     = p2.x;
        pk[2 * jj + 1] = p2.y;
      }
      lds[wbase + dyidx * P2_ + swz(pos)] = pk;
    }
    const float* a_base = in1 + ((size_t)(b * C_ + c0) * H_ + h) * W_ + w0;
    half2_t a2[8][4];
#pragma unroll
    for (int jj = 0; jj < 4; ++jj) {
      f4_t lo0 = *(const f4_t*)(a_base + (size_t)(2 * jj) * HW_);
      f4_t lo1 = *(const f4_t*)(a_base + (size_t)(2 * jj) * HW_ + 4);
      f4_t hi0 = *(const f4_t*)(a_base + (size_t)(2 * jj + 1) * HW_);
      f4_t hi1 = *(const f4_t*)(a_base + (size_t)(2 * jj + 1) * HW_ + 4);
#pragma unroll
      for (int j = 0; j < 4; ++j) {
        a2[j][jj]     = __builtin_amdgcn_cvt_pkrtz(lo0[j], hi0[j]);
        a2[j + 4][jj] = __builtin_amdgcn_cvt_pkrtz(lo1[j], hi1[j]);
      }
    }
    h8_t wv[8];
#pragma unroll
    for (int k = 0; k < 8; ++k)
      wv[k] = lds[ldsbase + swz(w0 + rel0 + k)];
#pragma unroll
    for (int i = 0; i < 11; ++i) {
#pragma unroll
      for (int j = 0; j < 8; ++j) {
        const h8_t wj = wv[(2 * i + j) & 7];
#pragma unroll
        for (int jj = 0; jj < 4; ++jj) {
          half2_t bb;
          bb.x = wj[2 * jj];
          bb.y = wj[2 * jj + 1];
          acc[j][i] = fdot2f(a2[j][jj], bb, acc[j][i]);
        }
      }
      if (i < 10) {
        wv[(2 * i + 8) & 7] = lds[ldsbase + swz(w0 + rel0 + 2 * i + 8)];
        wv[(2 * i + 9) & 7] = lds[ldsbase + swz(w0 + rel0 + 2 * i + 9)];
      }
    }
  }
  if (dy < PATCH_) {
    const float s = 1.f / (float)C_;
#pragma unroll
    for (int i = 0; i < 11; ++i) {
      if (q && i == 0) continue;
      const int dx = 10 * q + i;
      float* ob = out + ((size_t)(b * (PATCH_ * PATCH_) + dy * PATCH_ + dx) * H_ + h) * W_ + w0;
      f4_t v0, v1;
#pragma unroll
      for (int j = 0; j < 4; ++j) {
        float x = acc[j][i] * s;
        v0[j] = (x >= 0.f) ? x : 0.1f * x;
        float y = acc[j + 4][i] * s;
        v1[j] = (y >= 0.f) ? y : 0.1f * y;
      }
      *(f4_t*)ob = v0;
      *(f4_t*)(ob + 4) = v1;
    }
  }
}

extern "C" void kernel_launch(void* const* d_in, const int* in_sizes, int n_in,
                              void* d_out, int out_size, void* d_ws, size_t ws_size,
                              hipStream_t stream) {
  (void)in_sizes; (void)n_in; (void)out_size;
  const float* in1 = (const float*)d_in[0];
  const float* in2 = (const float*)d_in[1];
  float* out = (float*)d_out;

  if (ws_size >= WS_NEED_) {
    f16x8* ws1 = (f16x8*)d_ws;
    f16x8* ws2 = ws1 + NG1_;
    pack_kernel<<<dim3(2 * NPACKROW_), dim3(256), 0, stream>>>(in1, in2, ws1, ws2);
    corr_pp<<<dim3(NBLK2_), dim3(512), 0, stream>>>(ws1, ws2, out);
  } else {
    corr_kernel<<<dim3(NBLK_), dim3(256), 0, stream>>>(in1, in2, out);
  }
}